// Round 1
// baseline (546.264 us; speedup 1.0000x reference)
//
#include <hip/hip_runtime.h>

#define DAMPF 0.9998f

constexpr int T_len = 8192;
constexpr int NCH   = 64;            // chunks per (b,m) group
constexpr int CHLEN = T_len / NCH;   // 128
constexpr int TT    = 8;             // staging tile t-extent
constexpr int NTILE = CHLEN / TT;    // 16
constexpr int SF    = TT + 1;        // 9  (f/h LDS row stride, conflict-free)
constexpr int SP    = 17;            // partials LDS row stride

struct Tile4 { float4 fa, fb, ha, hb; };

__device__ __forceinline__ Tile4 load_tile(const float* Fp, const float* Hp,
                                           size_t half, int toff) {
  Tile4 t;
  t.fa = *(const float4*)(Fp + toff);
  t.fb = *(const float4*)(Fp + half + toff);
  t.ha = *(const float4*)(Hp + toff);
  t.hb = *(const float4*)(Hp + half + toff);
  return t;
}

__device__ __forceinline__ void store_tile(const Tile4& t, float* ftw, float* htw,
                                           int la, int la2) {
  ftw[la+0]=t.fa.x; ftw[la+1]=t.fa.y; ftw[la+2]=t.fa.z; ftw[la+3]=t.fa.w;
  ftw[la2+0]=t.fb.x; ftw[la2+1]=t.fb.y; ftw[la2+2]=t.fb.z; ftw[la2+3]=t.fb.w;
  htw[la+0]=t.ha.x; htw[la+1]=t.ha.y; htw[la+2]=t.ha.z; htw[la+3]=t.ha.w;
  htw[la2+0]=t.hb.x; htw[la2+1]=t.hb.y; htw[la2+2]=t.hb.z; htw[la2+3]=t.hb.w;
}

// ---------------- pass 1: zero-init chunk scan, emit zf = (pos, vel) ----------
__global__ __launch_bounds__(256) void goo_pass1(
    const float* __restrict__ F, const float* __restrict__ H,
    const float* __restrict__ tens, const float* __restrict__ mass,
    float* __restrict__ ws)
{
  __shared__ float ftile[4][64*SF];
  __shared__ float htile[4][64*SF];
  const int widx = threadIdx.x >> 6;
  const int lane = threadIdx.x & 63;
  const int w    = blockIdx.x * 4 + widx;   // 0..8191
  const int bm   = w >> 6;                  // / NCH
  const int c    = w & (NCH - 1);
  const int m    = bm & 63;
  const float k  = tens[m*64 + lane] / mass[m];

  float* ftw = ftile[widx];
  float* htw = htile[widx];
  const int row = lane >> 1;            // 0..31
  const int col = (lane & 1) * 4;       // 0 or 4
  const int la  = row*SF + col;
  const int la2 = la + 32*SF;
  const size_t half  = (size_t)32 * T_len;
  const size_t gbase = (size_t)bm * 64 * T_len + (size_t)c * CHLEN
                     + (size_t)row * T_len + col;
  const float* Fp = F + gbase;
  const float* Hp = H + gbase;
  const int dbase = lane * SF;

  float pos = 0.f, vel = 0.f;
  Tile4 cur = load_tile(Fp, Hp, half, 0);
  for (int tt = 0; tt < NTILE; ++tt) {
    store_tile(cur, ftw, htw, la, la2);
    __builtin_amdgcn_wave_barrier();
    if (tt + 1 < NTILE) cur = load_tile(Fp, Hp, half, (tt+1)*TT);
    #pragma unroll
    for (int t = 0; t < TT; ++t) {
      float ff = ftw[dbase + t];
      float hh = htw[dbase + t];
      float acc = fmaf(k, hh - pos, ff);
      vel = (vel + acc) * DAMPF;
      pos += vel;
    }
    __builtin_amdgcn_wave_barrier();
  }
  ws[(size_t)w*128 + lane]      = pos;
  ws[(size_t)w*128 + 64 + lane] = vel;
}

// ---------------- combine: x0[c] = A^L x0[c-1] + zf[c-1], in place ------------
__global__ __launch_bounds__(256) void goo_combine(
    const float* __restrict__ tens, const float* __restrict__ mass,
    float* __restrict__ ws)
{
  const int tid = blockIdx.x * 256 + threadIdx.x;  // 0..8191
  const int bm  = tid >> 6;
  const int d   = tid & 63;
  const int m   = bm & 63;
  const double k  = (double)tens[m*64 + d] / (double)mass[m];
  const double Dd = 0.9998;
  double a00 = 1.0 - Dd*k, a01 = Dd, a10 = -Dd*k, a11 = Dd;
  #pragma unroll
  for (int i = 0; i < 7; ++i) {      // A^(2^7) = A^128
    double b00 = a00*a00 + a01*a10;
    double b01 = a00*a01 + a01*a11;
    double b10 = a10*a00 + a11*a10;
    double b11 = a10*a01 + a11*a11;
    a00=b00; a01=b01; a10=b10; a11=b11;
  }
  double xp = 0.0, xv = 0.0;
  for (int c = 0; c < NCH; ++c) {
    const size_t base = ((size_t)bm*NCH + c)*128 + d;
    const float zp = ws[base];
    const float zv = ws[base + 64];
    ws[base]      = (float)xp;       // overwrite zf slot with x0
    ws[base + 64] = (float)xv;
    const double np = a00*xp + a01*xv + (double)zp;
    const double nv = a10*xp + a11*xv + (double)zv;
    xp = np; xv = nv;
  }
}

// ---------------- pass 2: true scan from x0, tanh-reduce, write out -----------
__global__ __launch_bounds__(256) void goo_pass2(
    const float* __restrict__ F, const float* __restrict__ H,
    const float* __restrict__ mic, const float* __restrict__ mass,
    const float* __restrict__ tens, const float* __restrict__ gains,
    const float* __restrict__ ws, float* __restrict__ out)
{
  __shared__ float ftile[4][64*SF];
  __shared__ float htile[4][64*SF];
  __shared__ float ptile[4][64*SP];
  const int widx = threadIdx.x >> 6;
  const int lane = threadIdx.x & 63;
  const int w    = blockIdx.x * 4 + widx;
  const int bm   = w >> 6;
  const int c    = w & (NCH - 1);
  const int m    = bm & 63;
  const float k       = tens[m*64 + lane] / mass[m];
  const float pregain = 2.0f * gains[m];
  const float micv    = mic[bm*64 + lane];
  const float m2n     = -2.0f * micv;

  float* ftw = ftile[widx];
  float* htw = htile[widx];
  float* plw = ptile[widx];
  const int row = lane >> 1;
  const int col = (lane & 1) * 4;
  const int la  = row*SF + col;
  const int la2 = la + 32*SF;
  const size_t half  = (size_t)32 * T_len;
  const size_t gbase = (size_t)bm * 64 * T_len + (size_t)c * CHLEN
                     + (size_t)row * T_len + col;
  const float* Fp = F + gbase;
  const float* Hp = H + gbase;
  const int dbase = lane * SF;

  float pos = ws[(size_t)w*128 + lane];
  float vel = ws[(size_t)w*128 + 64 + lane];

  Tile4 cur = load_tile(Fp, Hp, half, 0);
  for (int hi = 0; hi < 2; ++hi) {
    for (int tt = 0; tt < NTILE/2; ++tt) {
      const int gt = hi*(NTILE/2) + tt;
      store_tile(cur, ftw, htw, la, la2);
      __builtin_amdgcn_wave_barrier();
      if (gt + 1 < NTILE) cur = load_tile(Fp, Hp, half, (gt+1)*TT);
      #pragma unroll
      for (int t = 0; t < TT; ++t) {
        float ff = ftw[dbase + t];
        float hh = htw[dbase + t];
        float acc = fmaf(k, hh - pos, ff);
        vel = (vel + acc) * DAMPF;
        pos += vel;
        // tanh(g*v) = 1 - 2/(exp(2gv)+1); folded: y = mic - 2*mic*rcp(e+1)
        float e  = __expf(vel * pregain);
        float rr = __builtin_amdgcn_rcpf(e + 1.0f);
        float y  = fmaf(m2n, rr, micv);
        y += __shfl_xor(y, 1);
        y += __shfl_xor(y, 2);          // quad sums
        if ((lane & 3) == 0) plw[(tt*TT + t)*SP + (lane >> 2)] = y;
      }
      __builtin_amdgcn_wave_barrier();
    }
    float s = 0.f;
    #pragma unroll
    for (int i = 0; i < 16; ++i) s += plw[lane*SP + i];
    out[(size_t)bm*T_len + c*CHLEN + hi*64 + lane] = s;
    __builtin_amdgcn_wave_barrier();
  }
}

extern "C" void kernel_launch(void* const* d_in, const int* in_sizes, int n_in,
                              void* d_out, int out_size, void* d_ws, size_t ws_size,
                              hipStream_t stream)
{
  const float* F    = (const float*)d_in[0];  // forces   (B,M,D,T)
  const float* H    = (const float*)d_in[1];  // home_mod (B,M,D,T)
  const float* mic  = (const float*)d_in[2];  // (B,M,D,1)
  const float* mass = (const float*)d_in[3];  // (M,)
  const float* tens = (const float*)d_in[4];  // (M,D)
  const float* gain = (const float*)d_in[5];  // (M,)
  float* out = (float*)d_out;                 // (B,M,T,1) f32
  float* ws  = (float*)d_ws;                  // 4 MiB used: [128][64][2][64] f32

  goo_pass1  <<<2048, 256, 0, stream>>>(F, H, tens, mass, ws);
  goo_combine<<<  32, 256, 0, stream>>>(tens, mass, ws);
  goo_pass2  <<<2048, 256, 0, stream>>>(F, H, mic, mass, tens, gain, ws, out);
}

// Round 2
// 222.384 us; speedup vs baseline: 2.4564x; 2.4564x over previous
//
#include <hip/hip_runtime.h>

#define DAMPF 0.9998f

constexpr int T_len = 8192;
constexpr int NCH   = 64;            // chunks per (b,m) group
constexpr int CHLEN = T_len / NCH;   // 128
constexpr int TT    = 32;            // staging tile t-extent (= one 128B line/row)
constexpr int NTILE = CHLEN / TT;    // 4
constexpr int SF    = TT + 1;        // 33: padded row stride, conflict-free

// ---------------- pass 1: zero-init chunk scan, emit zf = (pos, vel) ----------
__global__ __launch_bounds__(128) void goo_pass1(
    const float* __restrict__ F, const float* __restrict__ H,
    const float* __restrict__ tens, const float* __restrict__ mass,
    float* __restrict__ ws)
{
  __shared__ float ftile[2][64*SF];
  __shared__ float htile[2][64*SF];
  const int widx = threadIdx.x >> 6;
  const int lane = threadIdx.x & 63;
  const int w    = blockIdx.x * 2 + widx;   // 0..8191
  const int bm   = w >> 6;
  const int c    = w & (NCH - 1);
  const int m    = bm & 63;
  const float k  = tens[m*64 + lane] / mass[m];

  float* ftw = ftile[widx];
  float* htw = htile[widx];
  const int r8 = lane >> 3;            // 0..7
  const int c4 = (lane & 7) * 4;       // 0..28
  const int la = r8*SF + c4;
  const size_t gbase = (size_t)bm * 64 * T_len + (size_t)c * CHLEN
                     + (size_t)r8 * T_len + c4;
  const float* Fp = F + gbase;
  const float* Hp = H + gbase;
  const int dbase = lane * SF;

  float4 pf[8], ph[8];
  auto load_tile = [&](int toff) {
    #pragma unroll
    for (int i = 0; i < 8; ++i) {
      pf[i] = *(const float4*)(Fp + (size_t)(8*i) * T_len + toff);
      ph[i] = *(const float4*)(Hp + (size_t)(8*i) * T_len + toff);
    }
  };
  auto store_tile = [&]() {
    #pragma unroll
    for (int i = 0; i < 8; ++i) {
      const int a = la + 8*i*SF;
      ftw[a+0]=pf[i].x; ftw[a+1]=pf[i].y; ftw[a+2]=pf[i].z; ftw[a+3]=pf[i].w;
      htw[a+0]=ph[i].x; htw[a+1]=ph[i].y; htw[a+2]=ph[i].z; htw[a+3]=ph[i].w;
    }
  };

  float pos = 0.f, vel = 0.f;
  load_tile(0);
  for (int tt = 0; tt < NTILE; ++tt) {
    store_tile();
    __builtin_amdgcn_wave_barrier();
    if (tt + 1 < NTILE) load_tile((tt+1)*TT);
    #pragma unroll
    for (int t = 0; t < TT; ++t) {
      float ff = ftw[dbase + t];
      float hh = htw[dbase + t];
      float acc = fmaf(k, hh - pos, ff);
      vel = (vel + acc) * DAMPF;
      pos += vel;
    }
    __builtin_amdgcn_wave_barrier();
  }
  ws[(size_t)w*128 + lane]      = pos;
  ws[(size_t)w*128 + 64 + lane] = vel;
}

// ---------------- combine: x0[c] = A^L x0[c-1] + zf[c-1], in place ------------
__global__ __launch_bounds__(256) void goo_combine(
    const float* __restrict__ tens, const float* __restrict__ mass,
    float* __restrict__ ws)
{
  const int tid = blockIdx.x * 256 + threadIdx.x;  // 0..8191
  const int bm  = tid >> 6;
  const int d   = tid & 63;
  const int m   = bm & 63;
  const double k  = (double)tens[m*64 + d] / (double)mass[m];
  const double Dd = 0.9998;
  double a00 = 1.0 - Dd*k, a01 = Dd, a10 = -Dd*k, a11 = Dd;
  #pragma unroll
  for (int i = 0; i < 7; ++i) {      // A^(2^7) = A^128
    double b00 = a00*a00 + a01*a10;
    double b01 = a00*a01 + a01*a11;
    double b10 = a10*a00 + a11*a10;
    double b11 = a10*a01 + a11*a11;
    a00=b00; a01=b01; a10=b10; a11=b11;
  }
  double xp = 0.0, xv = 0.0;
  for (int c = 0; c < NCH; ++c) {
    const size_t base = ((size_t)bm*NCH + c)*128 + d;
    const float zp = ws[base];
    const float zv = ws[base + 64];
    ws[base]      = (float)xp;       // overwrite zf slot with x0
    ws[base + 64] = (float)xv;
    const double np = a00*xp + a01*xv + (double)zp;
    const double nv = a10*xp + a11*xv + (double)zv;
    xp = np; xv = nv;
  }
}

// ---------------- pass 2: true scan from x0, tanh-reduce, write out -----------
__global__ __launch_bounds__(128) void goo_pass2(
    const float* __restrict__ F, const float* __restrict__ H,
    const float* __restrict__ mic, const float* __restrict__ mass,
    const float* __restrict__ tens, const float* __restrict__ gains,
    const float* __restrict__ ws, float* __restrict__ out)
{
  __shared__ float ftile[2][64*SF];
  __shared__ float htile[2][64*SF];
  const int widx = threadIdx.x >> 6;
  const int lane = threadIdx.x & 63;
  const int w    = blockIdx.x * 2 + widx;
  const int bm   = w >> 6;
  const int c    = w & (NCH - 1);
  const int m    = bm & 63;
  const float k       = tens[m*64 + lane] / mass[m];
  const float pregain = 2.0f * gains[m];
  const float micv    = mic[bm*64 + lane];
  const float m2n     = -2.0f * micv;

  float* ftw = ftile[widx];
  float* htw = htile[widx];
  const int r8 = lane >> 3;
  const int c4 = (lane & 7) * 4;
  const int la = r8*SF + c4;
  const size_t gbase = (size_t)bm * 64 * T_len + (size_t)c * CHLEN
                     + (size_t)r8 * T_len + c4;
  const float* Fp = F + gbase;
  const float* Hp = H + gbase;
  const int dbase = lane * SF;

  float4 pf[8], ph[8];
  auto load_tile = [&](int toff) {
    #pragma unroll
    for (int i = 0; i < 8; ++i) {
      pf[i] = *(const float4*)(Fp + (size_t)(8*i) * T_len + toff);
      ph[i] = *(const float4*)(Hp + (size_t)(8*i) * T_len + toff);
    }
  };
  auto store_tile = [&]() {
    #pragma unroll
    for (int i = 0; i < 8; ++i) {
      const int a = la + 8*i*SF;
      ftw[a+0]=pf[i].x; ftw[a+1]=pf[i].y; ftw[a+2]=pf[i].z; ftw[a+3]=pf[i].w;
      htw[a+0]=ph[i].x; htw[a+1]=ph[i].y; htw[a+2]=ph[i].z; htw[a+3]=ph[i].w;
    }
  };

  float pos = ws[(size_t)w*128 + lane];
  float vel = ws[(size_t)w*128 + 64 + lane];

  float keep = 0.f;
  load_tile(0);
  for (int tt = 0; tt < NTILE; ++tt) {
    store_tile();
    __builtin_amdgcn_wave_barrier();
    if (tt + 1 < NTILE) load_tile((tt+1)*TT);
    #pragma unroll
    for (int t = 0; t < TT; ++t) {
      float ff = ftw[dbase + t];
      float hh = htw[dbase + t];
      float acc = fmaf(k, hh - pos, ff);
      vel = (vel + acc) * DAMPF;
      pos += vel;
      // tanh(g*v) = 1 - 2/(exp(2gv)+1); folded: y = mic - 2*mic*rcp(e+1)
      float e  = __expf(vel * pregain);
      float rr = __builtin_amdgcn_rcpf(e + 1.0f);
      float y  = fmaf(m2n, rr, micv);
      y += __shfl_xor(y, 1);
      y += __shfl_xor(y, 2);
      y += __shfl_xor(y, 4);
      y += __shfl_xor(y, 8);
      y += __shfl_xor(y, 16);
      y += __shfl_xor(y, 32);          // all lanes now hold sum over d
      const int tmod = (tt & 1) * TT + t;      // 0..63 within window
      keep = (lane == tmod) ? y : keep;
    }
    __builtin_amdgcn_wave_barrier();
    if (tt & 1) {
      out[(size_t)bm*T_len + c*CHLEN + (tt>>1)*64 + lane] = keep;
    }
  }
}

extern "C" void kernel_launch(void* const* d_in, const int* in_sizes, int n_in,
                              void* d_out, int out_size, void* d_ws, size_t ws_size,
                              hipStream_t stream)
{
  const float* F    = (const float*)d_in[0];  // forces   (B,M,D,T)
  const float* H    = (const float*)d_in[1];  // home_mod (B,M,D,T)
  const float* mic  = (const float*)d_in[2];  // (B,M,D,1)
  const float* mass = (const float*)d_in[3];  // (M,)
  const float* tens = (const float*)d_in[4];  // (M,D)
  const float* gain = (const float*)d_in[5];  // (M,)
  float* out = (float*)d_out;                 // (B,M,T,1) f32
  float* ws  = (float*)d_ws;                  // 4 MiB used: [8192][2][64] f32

  goo_pass1  <<<4096, 128, 0, stream>>>(F, H, tens, mass, ws);
  goo_combine<<<  32, 256, 0, stream>>>(tens, mass, ws);
  goo_pass2  <<<4096, 128, 0, stream>>>(F, H, mic, mass, tens, gain, ws, out);
}